// Round 11
// baseline (2382.782 us; speedup 1.0000x reference)
//
#include <hip/hip_runtime.h>
#include <hip/hip_bf16.h>

// ---------------------------------------------------------------------------
// Per-head projection: out[tok, mat, h, d] = sum_e src[tok, h*64+e]*w[mat][e,d] + b[mat][d]
// One block per token row (512 elems). All fp32.
// ---------------------------------------------------------------------------
template<int NMAT>
__global__ __launch_bounds__(256) void proj_kernel(
    const float* __restrict__ src,
    const float* __restrict__ w0, const float* __restrict__ b0, float* __restrict__ o0,
    const float* __restrict__ w1, const float* __restrict__ b1, float* __restrict__ o1,
    const float* __restrict__ w2, const float* __restrict__ b2, float* __restrict__ o2)
{
    __shared__ float xs[512];
    const int t = threadIdx.x;
    const size_t tok = blockIdx.x;
    for (int i = t; i < 512; i += 256) xs[i] = src[tok * 512 + i];
    __syncthreads();
    #pragma unroll
    for (int it = 0; it < NMAT * 2; ++it) {
        int idx = t + it * 256;
        int mat = idx >> 9, r = idx & 511, h = r >> 6, d = r & 63;
        const float* w = (mat == 0) ? w0 : ((mat == 1) ? w1 : w2);
        const float* bb = (mat == 0) ? b0 : ((mat == 1) ? b1 : b2);
        float* o = (mat == 0) ? o0 : ((mat == 1) ? o1 : o2);
        const float* xh = &xs[h * 64];
        float acc = 0.f;
        #pragma unroll
        for (int e = 0; e < 64; ++e) acc += xh[e] * w[e * 64 + d];
        o[tok * 512 + r] = acc + bb[d];
    }
}

// ---------------------------------------------------------------------------
// Fused attention: logits -> mask -> softmax -> write aw (fp32) -> PV -> ctx
// Q,K,V fp32 [B,S,8,64]. Block = 8 q-rows of one (b,h). 256 threads.
// MASKROW=1: mask[q*SK+k] (causal), MASKROW=0: mask[b*SK+k] (padding).
// ---------------------------------------------------------------------------
template<int SK, int MASKROW>
__global__ __launch_bounds__(256) void attn_kernel(
    const float* __restrict__ Q, const float* __restrict__ K,
    const float* __restrict__ V, const float* __restrict__ mask,
    float scale, float* __restrict__ aw, float* __restrict__ ctx, int SQ)
{
    constexpr int QT = 8;
    __shared__ float qs[QT][64];
    __shared__ float lg[QT][SK];
    __shared__ float redm[4][QT];
    __shared__ float redv[4][QT][64];

    const int t = threadIdx.x, lane = t & 63, w = t >> 6;
    const int q0 = blockIdx.x * QT;
    const int h = blockIdx.y, b = blockIdx.z;

    {   // load 8 Q rows
        int qr = t >> 6;
        qs[qr][lane]     = Q[(((size_t)b * SQ + q0 + qr) * 8 + h) * 64 + lane];
        qs[qr + 4][lane] = Q[(((size_t)b * SQ + q0 + qr + 4) * 8 + h) * 64 + lane];
    }
    __syncthreads();

    const size_t kvbase = (size_t)b * SK * 512 + (size_t)h * 64;

    // ---- QK^T + scale + mask ----
    for (int i = 0; i < SK / 256; ++i) {
        int k = t + i * 256;
        const float4* kr = (const float4*)(K + kvbase + (size_t)k * 512);
        float acc[QT] = {};
        #pragma unroll
        for (int d4 = 0; d4 < 16; ++d4) {
            float4 kv = kr[d4];
            #pragma unroll
            for (int qr = 0; qr < QT; ++qr) {
                float4 qv = *(const float4*)&qs[qr][d4 * 4];
                acc[qr] += qv.x * kv.x + qv.y * kv.y + qv.z * kv.z + qv.w * kv.w;
            }
        }
        #pragma unroll
        for (int qr = 0; qr < QT; ++qr) {
            float mv;
            if (MASKROW) mv = mask[(size_t)(q0 + qr) * SK + k];
            else         mv = mask[(size_t)b * SK + k];
            lg[qr][k] = acc[qr] * scale + mv * (-1e9f);
        }
    }
    __syncthreads();

    // ---- softmax over each of the 8 rows ----
    float lm[QT];
    #pragma unroll
    for (int qr = 0; qr < QT; ++qr) lm[qr] = -3.0e38f;
    for (int i = 0; i < SK / 256; ++i) {
        int k = t + i * 256;
        #pragma unroll
        for (int qr = 0; qr < QT; ++qr) lm[qr] = fmaxf(lm[qr], lg[qr][k]);
    }
    #pragma unroll
    for (int qr = 0; qr < QT; ++qr)
        for (int off = 32; off >= 1; off >>= 1)
            lm[qr] = fmaxf(lm[qr], __shfl_xor(lm[qr], off));
    if (lane == 0) {
        #pragma unroll
        for (int qr = 0; qr < QT; ++qr) redm[w][qr] = lm[qr];
    }
    __syncthreads();
    float mrow[QT];
    #pragma unroll
    for (int qr = 0; qr < QT; ++qr)
        mrow[qr] = fmaxf(fmaxf(redm[0][qr], redm[1][qr]), fmaxf(redm[2][qr], redm[3][qr]));

    float ls[QT] = {};
    for (int i = 0; i < SK / 256; ++i) {
        int k = t + i * 256;
        #pragma unroll
        for (int qr = 0; qr < QT; ++qr) {
            float e = __expf(lg[qr][k] - mrow[qr]);
            lg[qr][k] = e;
            ls[qr] += e;
        }
    }
    __syncthreads();   // all threads have consumed redm; safe to overwrite
    #pragma unroll
    for (int qr = 0; qr < QT; ++qr)
        for (int off = 32; off >= 1; off >>= 1)
            ls[qr] += __shfl_xor(ls[qr], off);
    if (lane == 0) {
        #pragma unroll
        for (int qr = 0; qr < QT; ++qr) redm[w][qr] = ls[qr];
    }
    __syncthreads();
    float inv[QT];
    #pragma unroll
    for (int qr = 0; qr < QT; ++qr)
        inv[qr] = 1.0f / (redm[0][qr] + redm[1][qr] + redm[2][qr] + redm[3][qr]);

    // ---- write aw (fp32) + keep normalized p in LDS ----
    float* awb = aw + ((size_t)(b * 8 + h) * SQ + q0) * SK;
    for (int i = 0; i < SK / 256; ++i) {
        int k = t + i * 256;
        #pragma unroll
        for (int qr = 0; qr < QT; ++qr) {
            float p = lg[qr][k] * inv[qr];
            lg[qr][k] = p;
            awb[(size_t)qr * SK + k] = p;
        }
    }
    __syncthreads();

    // ---- PV: each wave covers a contiguous quarter of k ----
    const int d = lane;
    float acc[QT] = {};
    const int kc = SK / 4;
    for (int k = w * kc; k < (w + 1) * kc; k += 4) {
        float p[QT][4];
        #pragma unroll
        for (int qr = 0; qr < QT; ++qr) {
            float4 pv = *(const float4*)&lg[qr][k];
            p[qr][0] = pv.x; p[qr][1] = pv.y; p[qr][2] = pv.z; p[qr][3] = pv.w;
        }
        #pragma unroll
        for (int j = 0; j < 4; ++j) {
            float v = V[kvbase + (size_t)(k + j) * 512 + d];
            #pragma unroll
            for (int qr = 0; qr < QT; ++qr) acc[qr] += p[qr][j] * v;
        }
    }
    #pragma unroll
    for (int qr = 0; qr < QT; ++qr) redv[w][qr][lane] = acc[qr];
    __syncthreads();
    #pragma unroll
    for (int ii = 0; ii < 2; ++ii) {
        int idx = t + ii * 256;
        int qr = idx >> 6, dd = idx & 63;
        float s = redv[0][qr][dd] + redv[1][qr][dd] + redv[2][qr][dd] + redv[3][qr][dd];
        ctx[(((size_t)b * SQ + q0 + qr) * 8 + h) * 64 + dd] = s;
    }
}

// ---------------------------------------------------------------------------
// Tiled fp32 GEMM: C[M,N] = act(A[M,K] @ W[K,N] + bias). All fp32.
// 64x64 tile per block, 256 threads, each thread 4x4 outputs, TK=16.
// ---------------------------------------------------------------------------
template<int ACT>
__global__ __launch_bounds__(256) void gemm_kernel(
    const float* __restrict__ A, const float* __restrict__ W,
    const float* __restrict__ bias, float* __restrict__ C,
    int M, int N, int K)
{
    __shared__ float As[16][64];
    __shared__ float Ws[16][64];
    const int t = threadIdx.x;
    const int tx = t & 15, ty = t >> 4;
    const int n0 = blockIdx.x * 64, m0 = blockIdx.y * 64;
    const int lm = t >> 2, lk = (t & 3) * 4;
    float acc[4][4] = {};

    for (int k0 = 0; k0 < K; k0 += 16) {
        float4 av = *(const float4*)&A[(size_t)(m0 + lm) * K + k0 + lk];
        As[lk + 0][lm] = av.x; As[lk + 1][lm] = av.y;
        As[lk + 2][lm] = av.z; As[lk + 3][lm] = av.w;
        #pragma unroll
        for (int it = 0; it < 4; ++it) {
            int idx = t + it * 256;
            int kk = idx >> 6, nn = idx & 63;
            Ws[kk][nn] = W[(size_t)(k0 + kk) * N + n0 + nn];
        }
        __syncthreads();
        #pragma unroll
        for (int kk = 0; kk < 16; ++kk) {
            float4 a4 = *(const float4*)&As[kk][ty * 4];
            float4 w4 = *(const float4*)&Ws[kk][tx * 4];
            float a_[4] = {a4.x, a4.y, a4.z, a4.w};
            float w_[4] = {w4.x, w4.y, w4.z, w4.w};
            #pragma unroll
            for (int i = 0; i < 4; ++i)
                #pragma unroll
                for (int j = 0; j < 4; ++j)
                    acc[i][j] += a_[i] * w_[j];
        }
        __syncthreads();
    }
    #pragma unroll
    for (int i = 0; i < 4; ++i) {
        int mm = m0 + ty * 4 + i;
        float4 o;
        float v0 = acc[i][0] + bias[n0 + tx * 4 + 0];
        float v1 = acc[i][1] + bias[n0 + tx * 4 + 1];
        float v2 = acc[i][2] + bias[n0 + tx * 4 + 2];
        float v3 = acc[i][3] + bias[n0 + tx * 4 + 3];
        if (ACT == 1) {
            v0 = fmaxf(v0, 0.f); v1 = fmaxf(v1, 0.f);
            v2 = fmaxf(v2, 0.f); v3 = fmaxf(v3, 0.f);
        }
        o.x = v0; o.y = v1; o.z = v2; o.w = v3;
        *(float4*)&C[(size_t)mm * N + n0 + tx * 4] = o;
    }
}

// ---------------------------------------------------------------------------
// Fused residual-add + LayerNorm over rows of 512. One wave per row. fp32.
// ---------------------------------------------------------------------------
__global__ __launch_bounds__(256) void addln_kernel(
    const float* __restrict__ A, const float* __restrict__ R,
    const float* __restrict__ g, const float* __restrict__ bb,
    float* __restrict__ out)
{
    const int t = threadIdx.x, lane = t & 63, w = t >> 6;
    const size_t row = (size_t)blockIdx.x * 4 + w;
    const float* ar = A + row * 512;
    const float* rr = R + row * 512;
    float x[8];
    #pragma unroll
    for (int c = 0; c < 2; ++c) {
        float4 v = ((const float4*)ar)[lane * 2 + c];
        float4 rv = ((const float4*)rr)[lane * 2 + c];
        x[c * 4 + 0] = v.x + rv.x; x[c * 4 + 1] = v.y + rv.y;
        x[c * 4 + 2] = v.z + rv.z; x[c * 4 + 3] = v.w + rv.w;
    }
    float s = 0.f;
    #pragma unroll
    for (int i = 0; i < 8; ++i) s += x[i];
    for (int off = 32; off >= 1; off >>= 1) s += __shfl_xor(s, off);
    const float mu = s * (1.f / 512.f);
    float vs = 0.f;
    #pragma unroll
    for (int i = 0; i < 8; ++i) { float d = x[i] - mu; vs += d * d; }
    for (int off = 32; off >= 1; off >>= 1) vs += __shfl_xor(vs, off);
    const float inv = rsqrtf(vs * (1.f / 512.f) + 1e-6f);
    #pragma unroll
    for (int c = 0; c < 2; ++c) {
        #pragma unroll
        for (int j = 0; j < 4; ++j) {
            int idx = (lane * 2 + c) * 4 + j;
            out[row * 512 + idx] = g[idx] * (x[c * 4 + j] - mu) * inv + bb[idx];
        }
    }
}

// ---------------------------------------------------------------------------
extern "C" void kernel_launch(void* const* d_in, const int* in_sizes, int n_in,
                              void* d_out, int out_size, void* d_ws, size_t ws_size,
                              hipStream_t stream)
{
    // inputs fp32 (reference dtype); outputs fp32 (reference output dtype)
    const float* x    = (const float*)d_in[0];
    const float* enc  = (const float*)d_in[1];
    const float* lam  = (const float*)d_in[2];   // [1,1,1024,1024]
    const float* pm   = (const float*)d_in[3];   // [4,1,1,1536]
    const float *wq1 = (const float*)d_in[4],  *bq1 = (const float*)d_in[5];
    const float *wk1 = (const float*)d_in[6],  *bk1 = (const float*)d_in[7];
    const float *wv1 = (const float*)d_in[8],  *bv1 = (const float*)d_in[9];
    const float *wo1 = (const float*)d_in[10], *bo1 = (const float*)d_in[11];
    const float *wq2 = (const float*)d_in[12], *bq2 = (const float*)d_in[13];
    const float *wk2 = (const float*)d_in[14], *bk2 = (const float*)d_in[15];
    const float *wv2 = (const float*)d_in[16], *bv2 = (const float*)d_in[17];
    const float *wo2 = (const float*)d_in[18], *bo2 = (const float*)d_in[19];
    const float *fw1 = (const float*)d_in[20], *fb1 = (const float*)d_in[21];
    const float *fw2 = (const float*)d_in[22], *fb2 = (const float*)d_in[23];
    const float *ln1g = (const float*)d_in[24], *ln1b = (const float*)d_in[25];
    const float *ln2g = (const float*)d_in[26], *ln2b = (const float*)d_in[27];
    const float *ln3g = (const float*)d_in[28], *ln3b = (const float*)d_in[29];

    // compact workspace: 14,680,064 floats = 56 MiB total
    // q [0, 2M) | k [2M, 5.24M) | v [5.24M, 8.39M) | ao [8.39M, 10.49M)
    // tt [10.49M, 12.58M) | o1 [12.58M, 14.68M)
    // o2 overlays q; ffh (8,388,608) exactly overlays k+v+ao; ffo overlays tt
    float* Wp = (float*)d_ws;
    float* q   = Wp;
    float* k   = Wp + 2097152;
    float* v   = Wp + 5242880;
    float* ao  = Wp + 8388608;
    float* tt  = Wp + 10485760;
    float* o1  = Wp + 12582912;
    float* o2  = q;
    float* ffh = k;
    float* ffo = tt;

    float* out3 = (float*)d_out;               // [4,1024,512]
    float* aw1  = out3 + 2097152;              // [4,8,1024,1024]
    float* aw2  = aw1 + 33554432;              // [4,8,1024,1536]

    const float sc1 = 1.0f / 32.0f;                 // 1/sqrt(1024)
    const float sc2 = 0.025515518153991442f;        // 1/sqrt(1536)

    // ---- MHA1 (self, causal) ----
    proj_kernel<3><<<4096, 256, 0, stream>>>(
        x, wq1, bq1, q, wk1, bk1, k, wv1, bv1, v);
    attn_kernel<1024, 1><<<dim3(128, 8, 4), 256, 0, stream>>>(
        q, k, v, lam, sc1, aw1, ao, 1024);
    gemm_kernel<0><<<dim3(8, 64), 256, 0, stream>>>(ao, wo1, bo1, tt, 4096, 512, 512);
    addln_kernel<<<1024, 256, 0, stream>>>(tt, x, ln1g, ln1b, o1);

    // ---- MHA2 (cross) ----
    proj_kernel<2><<<6144, 256, 0, stream>>>(
        enc, wk2, bk2, k, wv2, bv2, v, nullptr, nullptr, nullptr);
    proj_kernel<1><<<4096, 256, 0, stream>>>(
        o1, wq2, bq2, q, nullptr, nullptr, nullptr, nullptr, nullptr, nullptr);
    attn_kernel<1536, 0><<<dim3(128, 8, 4), 256, 0, stream>>>(
        q, k, v, pm, sc2, aw2, ao, 1024);
    gemm_kernel<0><<<dim3(8, 64), 256, 0, stream>>>(ao, wo2, bo2, tt, 4096, 512, 512);
    addln_kernel<<<1024, 256, 0, stream>>>(tt, o1, ln2g, ln2b, o2);

    // ---- FFN ----
    gemm_kernel<1><<<dim3(32, 64), 256, 0, stream>>>(o2, fw1, fb1, ffh, 4096, 2048, 512);
    gemm_kernel<0><<<dim3(8, 64), 256, 0, stream>>>(ffh, fw2, fb2, ffo, 4096, 512, 2048);
    addln_kernel<<<1024, 256, 0, stream>>>(ffo, o2, ln3g, ln3b, out3);
}